// Round 3
// baseline (104.597 us; speedup 1.0000x reference)
//
#include <hip/hip_runtime.h>
#include <hip/hip_bf16.h>

// Problem constants (from reference): BS=64, K=4, PTS=5, RES=28, STEPS=500
// All tensors are float32 (reference dtypes; harness threshold 0.02*max with
// no bf16 floor confirms). Output: (64,1,28,28) f32.
#define BSZ    64
#define KK     4
#define NPTS   5
#define RES    28
#define NSTEPS 500
#define NPIX   (RES * RES)      // 784
#define EPSV   1e-6f

// One block per (b,k) stroke. 256 threads, each owns up to 4 pixels.
// Phase A: stage the 500 Bezier curve points in LDS.
// Phase B: accumulate sum_t exp(-d2*inv) per pixel (LDS broadcast of curve).
// Epilogue: block max-reduce -> maxnorm -> tanh_norm(slope_strk) -> ws (f32).
__global__ __launch_bounds__(256) void strokes_kernel(
    const float* __restrict__ z_pres,
    const float* __restrict__ z_what,
    const float* __restrict__ z_where,
    const float* __restrict__ sigma_p,
    const float* __restrict__ slope_strk_p,
    float* __restrict__ ws)
{
    __shared__ float sCx[NSTEPS];
    __shared__ float sCy[NSTEPS];
    __shared__ float sRed[4];

    const int bk  = blockIdx.x;   // b*K + k
    const int tid = threadIdx.x;

    const float s   = z_where[bk * 3 + 0];
    const float shx = z_where[bk * 3 + 1];
    const float shy = z_where[bk * 3 + 2];

    float px[NPTS], py[NPTS];
#pragma unroll
    for (int p = 0; p < NPTS; ++p) {
        px[p] = z_what[(bk * NPTS + p) * 2 + 0] * s + shx;
        py[p] = z_what[(bk * NPTS + p) * 2 + 1] * s + shy;
    }

    // Phase A: Bernstein basis (degree 4) at t = i/499, dotted with ctrl pts.
    for (int t = tid; t < NSTEPS; t += 256) {
        float tt = (float)t * (1.0f / (float)(NSTEPS - 1));
        float u  = 1.0f - tt;
        float u2 = u * u, t2 = tt * tt;
        float c0 = u2 * u2;
        float c1 = 4.0f * tt * u2 * u;
        float c2 = 6.0f * t2 * u2;
        float c3 = 4.0f * t2 * tt * u;
        float c4 = t2 * t2;
        sCx[t] = c0 * px[0] + c1 * px[1] + c2 * px[2] + c3 * px[3] + c4 * px[4];
        sCy[t] = c0 * py[0] + c1 * py[1] + c2 * py[2] + c3 * py[3] + c4 * py[4];
    }
    __syncthreads();

    const float sigma = sigma_p[0];
    const float inv   = 1.0f / (2.0f * sigma * sigma);

    float gx[4], gy[4];
    bool  act[4];
#pragma unroll
    for (int sl = 0; sl < 4; ++sl) {
        int p   = tid + sl * 256;
        act[sl] = (p < NPIX);
        int pc  = act[sl] ? p : 0;   // inactive slots duplicate pixel 0 (harmless)
        gx[sl]  = (float)(pc % RES) * (1.0f / (float)(RES - 1));
        gy[sl]  = (float)(pc / RES) * (1.0f / (float)(RES - 1));
    }

    float acc[4] = {0.f, 0.f, 0.f, 0.f};
    for (int t = 0; t < NSTEPS; ++t) {
        float cx = sCx[t];   // LDS broadcast: all lanes same address, conflict-free
        float cy = sCy[t];
#pragma unroll
        for (int sl = 0; sl < 4; ++sl) {
            float dx = gx[sl] - cx;
            float dy = gy[sl] - cy;
            float d2 = dx * dx + dy * dy;
            acc[sl] += __expf(-d2 * inv);
        }
    }

    // Block max-reduction over the 784 pixel accumulators.
    float m = 0.f;
#pragma unroll
    for (int sl = 0; sl < 4; ++sl) m = fmaxf(m, acc[sl]);
    for (int off = 32; off > 0; off >>= 1)
        m = fmaxf(m, __shfl_down(m, off, 64));
    if ((tid & 63) == 0) sRed[tid >> 6] = m;
    __syncthreads();
    m = fmaxf(fmaxf(sRed[0], sRed[1]), fmaxf(sRed[2], sRed[3]));

    const float zp    = z_pres[bk];               // uniform[0,1) -> >= 0
    const float denom = 1.0f / (m * zp + EPSV);   // max(acc*zp) == max(acc)*zp
    const float sstrk = slope_strk_p[0];
    const float itnh  = 1.0f / tanhf(sstrk);

#pragma unroll
    for (int sl = 0; sl < 4; ++sl) {
        if (act[sl]) {
            float v = acc[sl] * zp * denom;
            ws[bk * NPIX + tid + sl * 256] = tanhf(v * sstrk) * itnh;
        }
    }
}

// Sum over K strokes + final tanh_norm(slope), write f32 output (64,1,28,28).
__global__ __launch_bounds__(256) void combine_kernel(
    const float* __restrict__ ws,
    const float* __restrict__ slope_p,
    float* __restrict__ out)
{
    int idx = blockIdx.x * 256 + threadIdx.x;
    if (idx >= BSZ * NPIX) return;
    int b = idx / NPIX;
    int p = idx - b * NPIX;
    const float* base = ws + b * (KK * NPIX) + p;
    float sum = (base[0] + base[NPIX]) + (base[2 * NPIX] + base[3 * NPIX]);
    float sl  = slope_p[0];
    float v   = tanhf(sum * sl) / tanhf(sl);
    out[idx] = v;   // f32 output — reference output dtype is float32
}

extern "C" void kernel_launch(void* const* d_in, const int* in_sizes, int n_in,
                              void* d_out, int out_size, void* d_ws, size_t ws_size,
                              hipStream_t stream) {
    const float* z_pres     = (const float*)d_in[0];
    const float* z_what     = (const float*)d_in[1];
    const float* z_where    = (const float*)d_in[2];
    const float* sigma      = (const float*)d_in[3];
    const float* slope_strk = (const float*)d_in[4];
    const float* slope      = (const float*)d_in[5];

    float* ws  = (float*)d_ws;          // BS*K*784 floats = 784 KB scratch
    float* out = (float*)d_out;

    strokes_kernel<<<BSZ * KK, 256, 0, stream>>>(z_pres, z_what, z_where,
                                                 sigma, slope_strk, ws);
    combine_kernel<<<(BSZ * NPIX + 255) / 256, 256, 0, stream>>>(ws, slope, out);
}

// Round 4
// 78.053 us; speedup vs baseline: 1.3401x; 1.3401x over previous
//
#include <hip/hip_runtime.h>
#include <hip/hip_bf16.h>

// Problem constants (from reference): BS=64, K=4, PTS=5, RES=28, STEPS=500
// All tensors float32. Output (64,1,28,28) f32.
//
// Round-3 counters: strokes was VALU-issue-bound (131M exp+8VALU elements) at
// 1 wave/SIMD (Occupancy 9%). Fix: separable Gaussian —
//   exp(-(dx^2+dy^2)inv) = exp(-dx^2 inv) * exp(-dy^2 inv)
// Precompute Ex[t][x], Ey[t][y] (28K exps/block vs 524K), then each pixel is
// a K=500 dot product fed from LDS (b128 Ex reads, broadcast Ey reads).
#define BSZ    64
#define KK     4
#define NPTS   5
#define RES    28
#define NSTEPS 500
#define NPIX   (RES * RES)      // 784
#define TCH    250              // t-chunk size (2 chunks); LDS budget < 64 KB
#define NCH    (NSTEPS / TCH)
#define EPSV   1e-6f

// One block per (b,k) stroke; 256 threads.
// Threads 0..195 each own 4 consecutive pixels of one row:
//   y = tid/7, x0 = (tid%7)*4   (28 = 7*4 per row)
__global__ __launch_bounds__(256) void strokes_kernel(
    const float* __restrict__ z_pres,
    const float* __restrict__ z_what,
    const float* __restrict__ z_where,
    const float* __restrict__ sigma_p,
    const float* __restrict__ slope_strk_p,
    float* __restrict__ ws)
{
    __shared__ float sCx[NSTEPS];
    __shared__ float sCy[NSTEPS];
    __shared__ __align__(16) float sEx[TCH * RES];   // Ex[t][x], row stride 28 (112B, 16B-mult)
    __shared__ __align__(16) float sEy[TCH * RES];   // Ey[t][y]
    __shared__ float sRed[4];

    const int bk  = blockIdx.x;   // b*K + k
    const int tid = threadIdx.x;

    const float s   = z_where[bk * 3 + 0];
    const float shx = z_where[bk * 3 + 1];
    const float shy = z_where[bk * 3 + 2];

    float px[NPTS], py[NPTS];
#pragma unroll
    for (int p = 0; p < NPTS; ++p) {
        px[p] = z_what[(bk * NPTS + p) * 2 + 0] * s + shx;
        py[p] = z_what[(bk * NPTS + p) * 2 + 1] * s + shy;
    }

    // Bernstein basis (degree 4) at t=i/499 dotted with ctrl pts -> LDS curve.
    for (int t = tid; t < NSTEPS; t += 256) {
        float tt = (float)t * (1.0f / (float)(NSTEPS - 1));
        float u  = 1.0f - tt;
        float u2 = u * u, t2 = tt * tt;
        float c0 = u2 * u2;
        float c1 = 4.0f * tt * u2 * u;
        float c2 = 6.0f * t2 * u2;
        float c3 = 4.0f * t2 * tt * u;
        float c4 = t2 * t2;
        sCx[t] = c0 * px[0] + c1 * px[1] + c2 * px[2] + c3 * px[3] + c4 * px[4];
        sCy[t] = c0 * py[0] + c1 * py[1] + c2 * py[2] + c3 * py[3] + c4 * py[4];
    }
    __syncthreads();

    const float sigma = sigma_p[0];
    const float inv   = 1.0f / (2.0f * sigma * sigma);

    const bool  own = (tid < 196);
    const int   y   = tid / 7;             // valid when own
    const int   x0  = (tid % 7) * 4;
    const float gy  = (float)y * (1.0f / (float)(RES - 1));
    float gx[4];
#pragma unroll
    for (int j = 0; j < 4; ++j) gx[j] = (float)(x0 + j) * (1.0f / (float)(RES - 1));
    (void)gy; (void)gx;   // used below

    float acc[4] = {0.f, 0.f, 0.f, 0.f};

    for (int c = 0; c < NCH; ++c) {
        const int tbase = c * TCH;
        // Fill Ex/Ey for this chunk: 2 exps per (t,x) slot, 7000 slots.
        for (int i = tid; i < TCH * RES; i += 256) {
            int t = i / RES;
            int x = i - t * RES;
            float g   = (float)x * (1.0f / (float)(RES - 1));
            float cx  = sCx[tbase + t];
            float cy  = sCy[tbase + t];
            float dxx = g - cx;
            float dyy = g - cy;
            sEx[i] = __expf(-dxx * dxx * inv);
            sEy[i] = __expf(-dyy * dyy * inv);
        }
        __syncthreads();

        if (own) {
            const float* ebase = sEx + x0;
            const float* ybase = sEy + y;
            for (int t = 0; t < TCH; ++t) {
                float  ey = ybase[t * RES];                       // broadcast-ish b32
                float4 ex = *(const float4*)(ebase + t * RES);    // b128, 16B-aligned
                acc[0] += ey * ex.x;
                acc[1] += ey * ex.y;
                acc[2] += ey * ex.z;
                acc[3] += ey * ex.w;
            }
        }
        __syncthreads();   // protect sEx/sEy before next chunk refill
    }

    // Block max-reduction (inactive threads hold 0; all values >= 0).
    float m = 0.f;
#pragma unroll
    for (int sl = 0; sl < 4; ++sl) m = fmaxf(m, acc[sl]);
    for (int off = 32; off > 0; off >>= 1)
        m = fmaxf(m, __shfl_down(m, off, 64));
    if ((tid & 63) == 0) sRed[tid >> 6] = m;
    __syncthreads();
    m = fmaxf(fmaxf(sRed[0], sRed[1]), fmaxf(sRed[2], sRed[3]));

    const float zp    = z_pres[bk];               // uniform[0,1) -> >= 0
    const float denom = 1.0f / (m * zp + EPSV);   // max(acc*zp) == max(acc)*zp
    const float sstrk = slope_strk_p[0];
    const float itnh  = 1.0f / tanhf(sstrk);

    if (own) {
        float4 o;
        o.x = tanhf(acc[0] * zp * denom * sstrk) * itnh;
        o.y = tanhf(acc[1] * zp * denom * sstrk) * itnh;
        o.z = tanhf(acc[2] * zp * denom * sstrk) * itnh;
        o.w = tanhf(acc[3] * zp * denom * sstrk) * itnh;
        *(float4*)(ws + bk * NPIX + tid * 4) = o;   // 3136B/stroke, 16B-aligned
    }
}

// Sum over K strokes + final tanh_norm(slope), write f32 output (64,1,28,28).
__global__ __launch_bounds__(256) void combine_kernel(
    const float* __restrict__ ws,
    const float* __restrict__ slope_p,
    float* __restrict__ out)
{
    int idx = blockIdx.x * 256 + threadIdx.x;
    if (idx >= BSZ * NPIX) return;
    int b = idx / NPIX;
    int p = idx - b * NPIX;
    const float* base = ws + b * (KK * NPIX) + p;
    float sum = (base[0] + base[NPIX]) + (base[2 * NPIX] + base[3 * NPIX]);
    float sl  = slope_p[0];
    out[idx] = tanhf(sum * sl) / tanhf(sl);
}

extern "C" void kernel_launch(void* const* d_in, const int* in_sizes, int n_in,
                              void* d_out, int out_size, void* d_ws, size_t ws_size,
                              hipStream_t stream) {
    const float* z_pres     = (const float*)d_in[0];
    const float* z_what     = (const float*)d_in[1];
    const float* z_where    = (const float*)d_in[2];
    const float* sigma      = (const float*)d_in[3];
    const float* slope_strk = (const float*)d_in[4];
    const float* slope      = (const float*)d_in[5];

    float* ws  = (float*)d_ws;          // BS*K*784 floats = 784 KB scratch
    float* out = (float*)d_out;

    strokes_kernel<<<BSZ * KK, 256, 0, stream>>>(z_pres, z_what, z_where,
                                                 sigma, slope_strk, ws);
    combine_kernel<<<(BSZ * NPIX + 255) / 256, 256, 0, stream>>>(ws, slope, out);
}